// Round 2
// baseline (146.301 us; speedup 1.0000x reference)
//
#include <hip/hip_runtime.h>

#define BN 4
#define CH 64          // CIN*UM = COUT*UM
#define HH 128
#define WW 128
#define PIX (HH*WW)

// workspace layout (float offsets)
#define OFF_WL  0                    // [64][9][64]  = 36864
#define OFF_S   36864                // [2][64]      = 128
#define OFF_CS  36992                // [4][2][128][128] = 131072
#define OFF_AVG 168064               // [4][2][128][128] = 131072
// total 299136 floats = 1.17 MB

// ---- tiny: effective conv weights Wl[c][tap][oc] = ker[oc, c, p, q], tap = q*3+p
__global__ void k_weights(const float* __restrict__ params,
                          const float* __restrict__ basis,
                          float* __restrict__ Wl) {
    int idx = blockIdx.x * blockDim.x + threadIdx.x;
    if (idx >= 64 * 9 * 64) return;
    int oc  = idx & 63;
    int tap = (idx >> 6) % 9;
    int c   = idx / (64 * 9);
    int q = tap / 3, p = tap % 3;
    int o = oc >> 1, g = oc & 1;
    int i = c >> 1, u = c & 1;
    float s = 0.f;
    #pragma unroll
    for (int n = 0; n < 4; ++n)
        #pragma unroll
        for (int d = 0; d < 4; ++d)
            s = fmaf(params[((o * 32 + i) * 4 + n) * 4 + d],
                     basis[((((n * 4 + d) * 3 + p) * 3 + q) * 2 + g) * 2 + u], s);
    Wl[idx] = s;
}

// ---- S[u][oc] = sum over i, taps of Wl
__global__ void k_ssum(const float* __restrict__ Wl, float* __restrict__ S) {
    int t = threadIdx.x;
    if (t >= 128) return;
    int u = t >> 6, oc = t & 63;
    float s = 0.f;
    for (int i = 0; i < 32; ++i)
        for (int tap = 0; tap < 9; ++tap)
            s += Wl[((i * 2 + u) * 9 + tap) * 64 + oc];
    S[t] = s;
}

// ---- cs[b][u][h][w] = sum_i x[b][2i+u][h][w]
__global__ void k_colsum(const float* __restrict__ x, float* __restrict__ cs) {
    int idx = blockIdx.x * blockDim.x + threadIdx.x;
    if (idx >= BN * 2 * PIX) return;
    int pix = idx & (PIX - 1);
    int u   = (idx >> 14) & 1;
    int b   = idx >> 15;
    const float* xb = x + b * CH * PIX + u * PIX + pix;
    float s = 0.f;
    #pragma unroll
    for (int i = 0; i < 32; ++i) s += xb[i * 2 * PIX];
    cs[idx] = s;
}

// ---- avg[b][u][h][w] = box3x3_edge(cs)/288
__global__ void k_avg(const float* __restrict__ cs, float* __restrict__ avg) {
    int idx = blockIdx.x * blockDim.x + threadIdx.x;
    if (idx >= BN * 2 * PIX) return;
    int w  = idx & (WW - 1);
    int h  = (idx >> 7) & (HH - 1);
    int bu = idx >> 14;
    const float* c0 = cs + bu * PIX;
    int hm = h > 0 ? h - 1 : 0, hp = h < HH - 1 ? h + 1 : HH - 1;
    int wm = w > 0 ? w - 1 : 0, wp = w < WW - 1 ? w + 1 : WW - 1;
    float s = c0[hm * WW + wm] + c0[hm * WW + w] + c0[hm * WW + wp]
            + c0[h  * WW + wm] + c0[h  * WW + w] + c0[h  * WW + wp]
            + c0[hp * WW + wm] + c0[hp * WW + w] + c0[hp * WW + wp];
    avg[idx] = s * (1.0f / 288.0f);
}

// ---- main: direct 3x3 conv (64->16 oc per block) + fused epilogue
__global__ __launch_bounds__(256) void k_main(
    const float* __restrict__ x,     // [4][64][128][128]
    const float* __restrict__ Wl,    // [64][9][64]
    const float* __restrict__ S,     // [2][64]
    const float* __restrict__ bias,  // [64]  (bias_term flat: o*2+g)
    const float* __restrict__ avg,   // [4][2][128][128]
    const float* __restrict__ bptr,  // scalar b
    float* __restrict__ out)         // [4][64][128][128]
{
    int tile   = blockIdx.x;          // 8x8 tiles of 16x16
    int ocbase = blockIdx.y * 16;
    int b      = blockIdx.z;
    int ty = threadIdx.x >> 4, tx = threadIdx.x & 15;
    int h = (tile >> 3) * 16 + ty;
    int w = (tile & 7) * 16 + tx;

    int hm = h > 0 ? h - 1 : 0, hp = h < HH - 1 ? h + 1 : HH - 1;
    int wm = w > 0 ? w - 1 : 0, wp = w < WW - 1 ? w + 1 : WW - 1;
    int rowoff[3] = { hm * WW, h * WW, hp * WW };
    int coloff[3] = { wm, w, wp };

    float acc[16];
    #pragma unroll
    for (int j = 0; j < 16; ++j) acc[j] = 0.f;

    const float* xc = x + b * CH * PIX;
    const float* wc = Wl + ocbase;
    for (int c = 0; c < CH; ++c) {
        float xv[9];
        #pragma unroll
        for (int q = 0; q < 3; ++q)
            #pragma unroll
            for (int p = 0; p < 3; ++p)
                xv[q * 3 + p] = xc[rowoff[q] + coloff[p]];
        #pragma unroll
        for (int t = 0; t < 9; ++t) {
            #pragma unroll
            for (int j = 0; j < 16; ++j)
                acc[j] = fmaf(xv[t], wc[t * 64 + j], acc[j]);
        }
        xc += PIX;
        wc += 9 * 64;
    }

    int pix = h * WW + w;
    float a0 = avg[(b * 2 + 0) * PIX + pix];
    float a1 = avg[(b * 2 + 1) * PIX + pix];
    float bthr = bptr[0];

    float t[16];
    #pragma unroll
    for (int j = 0; j < 16; ++j) {
        int oc = ocbase + j;
        t[j] = acc[j] - a0 * S[oc] - a1 * S[64 + oc] + bias[oc];
    }

    float* ob = out + b * CH * PIX + pix;
    #pragma unroll
    for (int j = 0; j < 16; j += 2) {
        float n = sqrtf(t[j] * t[j] + t[j + 1] * t[j + 1]);
        float r0, r1;
        if (n - bthr <= 0.f) { r0 = 0.f; r1 = 0.f; }
        else { r0 = t[j] / n; r1 = t[j + 1] / n; }
        ob[(ocbase + j)     * PIX] = r0 + a0;
        ob[(ocbase + j + 1) * PIX] = r1 + a1;
    }
}

extern "C" void kernel_launch(void* const* d_in, const int* in_sizes, int n_in,
                              void* d_out, int out_size, void* d_ws, size_t ws_size,
                              hipStream_t stream) {
    const float* xx     = (const float*)d_in[0];
    const float* params = (const float*)d_in[1];
    const float* basis  = (const float*)d_in[2];
    const float* bias   = (const float*)d_in[3];
    const float* bptr   = (const float*)d_in[4];
    float* out = (float*)d_out;
    float* ws  = (float*)d_ws;

    float* Wl  = ws + OFF_WL;
    float* S   = ws + OFF_S;
    float* cs  = ws + OFF_CS;
    float* avg = ws + OFF_AVG;

    k_weights<<<(64 * 9 * 64 + 255) / 256, 256, 0, stream>>>(params, basis, Wl);
    k_ssum<<<1, 128, 0, stream>>>(Wl, S);
    k_colsum<<<(BN * 2 * PIX + 255) / 256, 256, 0, stream>>>(xx, cs);
    k_avg<<<(BN * 2 * PIX + 255) / 256, 256, 0, stream>>>(cs, avg);

    dim3 grid(64, 4, BN);
    k_main<<<grid, 256, 0, stream>>>(xx, Wl, S, bias, avg, bptr, out);
}